// Round 5
// baseline (19040.990 us; speedup 1.0000x reference)
//
#include <hip/hip_runtime.h>
#include <math.h>

#define NBLK 256
#define NTHR 512

// ws float offsets (cross-block data via device-scope sc1 ops)
#define OFF_HX  0               // [8][1024]
#define OFF_H0  8192            // [8][1024]
#define OFF_CTX 16384           // [8][1024]
#define OFF_Z   24576           // [4][8][1024]
#define OFF_KB  65536           // [256][8][1024]
#define OFF_VB  (OFF_KB + 2097152)
#define OFF_BAR (OFF_VB + 2097152)   // 1024 floats: 8 group ctrs (128B apart) + glob
#define OFF_ZX  (OFF_BAR + 1024)     // [16][4][8][1024] window x-part of z (incl bias)

// LDS float offsets
#define S_WG    0                // 16 rows x 2048 fp32 (128KB)
#define S_HX    32768            // 4096 (hx/z/h0 staging)
#define S_CX    36864            // 1024 (persistent cx, blocks 0..7)
#define S_RED   37888            // 32
#define S_Q     37920            // 64
#define S_PS    37984            // 256
#define S_R2    38240            // 16
#define S_CTXP  38256            // 1024 ([16][64])
#define LDS_FLOATS 39280
#define LDS_BYTES  (LDS_FLOATS * 4)

typedef unsigned long long u64;
union F2U { u64 u; float2 f; };

__device__ __forceinline__ float ld1(const float* p) {
    return __hip_atomic_load(const_cast<float*>(p), __ATOMIC_RELAXED, __HIP_MEMORY_SCOPE_AGENT);
}
__device__ __forceinline__ void st1(float* p, float v) {
    __hip_atomic_store(p, v, __ATOMIC_RELAXED, __HIP_MEMORY_SCOPE_AGENT);
}
__device__ __forceinline__ float2 ld2(const float* p) {
    F2U c; c.u = __hip_atomic_load(reinterpret_cast<u64*>(const_cast<float*>(p)),
                                   __ATOMIC_RELAXED, __HIP_MEMORY_SCOPE_AGENT);
    return c.f;
}
__device__ __forceinline__ float4 ld4(const float* p) {
    float2 a = ld2(p), b = ld2(p + 2);
    return make_float4(a.x, a.y, b.x, b.y);
}
__device__ __forceinline__ float dot4(const float4 a, const float4 b) {
    return a.x*b.x + a.y*b.y + a.z*b.z + a.w*b.w;
}

// Two-level monotonic relaxed-atomic grid barrier (8 groups of 32).
__device__ __forceinline__ void gsync(unsigned* barbase, unsigned bc, int blk) {
    __syncthreads();
    if (threadIdx.x == 0) {
        asm volatile("" ::: "memory");
        unsigned* grp  = barbase + ((blk >> 5) << 5);   // 128B apart
        unsigned* glob = barbase + 256;
        const unsigned a = __hip_atomic_fetch_add(grp, 1u, __ATOMIC_RELAXED, __HIP_MEMORY_SCOPE_AGENT);
        if (a == bc * 32u - 1u)
            __hip_atomic_fetch_add(glob, 1u, __ATOMIC_RELAXED, __HIP_MEMORY_SCOPE_AGENT);
        while (__hip_atomic_load(glob, __ATOMIC_RELAXED, __HIP_MEMORY_SCOPE_AGENT) < bc * 8u)
            __builtin_amdgcn_s_sleep(4);
        asm volatile("" ::: "memory");
    }
    __syncthreads();
}

__global__ __launch_bounds__(NTHR, 1)
void qlstm_kernel(const float* __restrict__ x,  const float* __restrict__ Wg,
                  const float* __restrict__ bg, const float* __restrict__ lng,
                  const float* __restrict__ lnb,const float* __restrict__ Wq,
                  const float* __restrict__ Wk, const float* __restrict__ Wv,
                  const float* __restrict__ bq, const float* __restrict__ bk,
                  const float* __restrict__ bv, const float* __restrict__ Wo,
                  const float* __restrict__ bo, float* __restrict__ out,
                  float* __restrict__ ws)
{
    extern __shared__ float lds[];
    const int blk = blockIdx.x, tid = threadIdx.x;
    const int w = tid >> 6, l = tid & 63;

    float* hx  = ws + OFF_HX;   float* h0 = ws + OFF_H0;
    float* ctx = ws + OFF_CTX;  float* z  = ws + OFF_Z;
    float* Kb  = ws + OFF_KB;   float* Vb = ws + OFF_VB;
    float* zx  = ws + OFF_ZX;
    unsigned* bar = (unsigned*)(ws + OFF_BAR);
    unsigned bc = 0;

    // ---- preload Wg slice (16 rows x 2048 fp32) into LDS ----
    {
        const float* wsrc = Wg + (size_t)blk * 32768;
        #pragma unroll
        for (int j = 0; j < 16; ++j) {
            const int fi = j * 512 + tid;
            *(float4*)(lds + S_WG + fi * 4) = *(const float4*)(wsrc + fi * 4);
        }
    }
    // ---- K/V-proj weights: 1 row per wave, in VGPRs ----
    const int kv_row = blk * 8 + w;
    const int kv_mat = kv_row >> 10, kv_h = kv_row & 1023;
    const float* kv_wrow = (kv_mat ? Wv : Wk) + (size_t)kv_h * 1024;
    float4 wkv[4];
    #pragma unroll
    for (int i = 0; i < 4; ++i) wkv[i] = *(const float4*)(kv_wrow + i * 256 + l * 4);
    const float kv_bias = (kv_mat ? bv : bk)[kv_h];
    // ---- this block's gate rows: gate g, rows h0r, h0r+1 per wave ----
    const int g   = blk >> 6;
    const int h0r = (blk & 63) * 16 + 2 * w;
    const float bg0 = bg[g * 1024 + h0r], bg1 = bg[g * 1024 + h0r + 1];
    // ---- out-proj rows blk*4..+3 (wave = batch) ----
    const float bo0 = bo[blk*4+0], bo1 = bo[blk*4+1], bo2 = bo[blk*4+2], bo3 = bo[blk*4+3];

    // ---- init: zero hx, zero LDS cx ----
    { const int idx = blk * NTHR + tid; if (idx < 8192) st1(hx + idx, 0.f); }
    if (blk < 8 && tid < 256) *(float4*)(lds + S_CX + tid * 4) = make_float4(0,0,0,0);
    gsync(bar, ++bc, blk);

    for (int t = 0; t < 256; ++t) {
        // ===== Bulk: window x-part of gate GEMV, zx[tt] = Wg_x·x[t+tt] + bg =====
        if ((t & 15) == 0) {
            const float* xw = x + (size_t)t * 8192;
            #pragma unroll 2
            for (int tt = 0; tt < 16; ++tt) {
                float b0[8], b1[8];
                #pragma unroll
                for (int b = 0; b < 8; ++b) { b0[b] = 0.f; b1[b] = 0.f; }
                #pragma unroll
                for (int i = 0; i < 4; ++i) {
                    const int k = i * 256 + l * 4;
                    const float4 w0 = *(const float4*)(lds + S_WG + (2*w)   * 2048 + k);
                    const float4 w1 = *(const float4*)(lds + S_WG + (2*w+1) * 2048 + k);
                    #pragma unroll
                    for (int b = 0; b < 8; ++b) {
                        const float4 a = *(const float4*)(xw + (size_t)tt * 8192 + b * 1024 + k);
                        b0[b] += dot4(w0, a); b1[b] += dot4(w1, a);
                    }
                }
                #pragma unroll
                for (int o = 1; o < 64; o <<= 1)
                    #pragma unroll
                    for (int b = 0; b < 8; ++b) {
                        b0[b] += __shfl_xor(b0[b], o); b1[b] += __shfl_xor(b1[b], o);
                    }
                if (l == 0) {
                    float* zd = zx + ((size_t)tt * 4 + g) * 8192;
                    #pragma unroll
                    for (int b = 0; b < 8; ++b) {
                        st1(zd + b * 1024 + h0r,     b0[b] + bg0);
                        st1(zd + b * 1024 + h0r + 1, b1[b] + bg1);
                    }
                }
            }
            gsync(bar, ++bc, blk);
        }

        // ===== Phase A: hx-part gate GEMV + KV proj; z = zx + acc =====
        {
            float zp0[8], zp1[8];
            if (l == 0) {
                const float* zs = zx + ((size_t)(t & 15) * 4 + g) * 8192;
                #pragma unroll
                for (int b = 0; b < 8; ++b) {
                    zp0[b] = ld1(zs + b * 1024 + h0r);
                    zp1[b] = ld1(zs + b * 1024 + h0r + 1);
                }
            }
            float a0[8], a1[8], akv[8];
            #pragma unroll
            for (int b = 0; b < 8; ++b) { a0[b] = 0.f; a1[b] = 0.f; akv[b] = 0.f; }
            if (t > 0) {
                #pragma unroll
                for (int c = 0; c < 2; ++c) {
                    __syncthreads();
                    #pragma unroll
                    for (int j = 0; j < 4; ++j) {
                        const int fi = tid * 8 + j * 2;
                        const int b = fi >> 9, off = fi & 511;
                        *(float2*)(lds + S_HX + fi) = ld2(hx + b * 1024 + c * 512 + off);
                    }
                    __syncthreads();
                    #pragma unroll
                    for (int ii = 0; ii < 2; ++ii) {
                        const int i = c * 2 + ii;
                        const int k = ii * 256 + l * 4;
                        const float4 w0 = *(const float4*)(lds + S_WG + (2*w)   * 2048 + 1024 + c * 512 + k);
                        const float4 w1 = *(const float4*)(lds + S_WG + (2*w+1) * 2048 + 1024 + c * 512 + k);
                        const float4 wk = wkv[i];
                        #pragma unroll
                        for (int b = 0; b < 8; ++b) {
                            const float4 a = *(const float4*)(lds + S_HX + b * 512 + k);
                            a0[b] += dot4(w0, a); a1[b] += dot4(w1, a); akv[b] += dot4(wk, a);
                        }
                    }
                }
                #pragma unroll
                for (int o = 1; o < 64; o <<= 1)
                    #pragma unroll
                    for (int b = 0; b < 8; ++b) {
                        a0[b] += __shfl_xor(a0[b], o);
                        a1[b] += __shfl_xor(a1[b], o);
                        akv[b] += __shfl_xor(akv[b], o);
                    }
            }
            if (l == 0) {
                #pragma unroll
                for (int b = 0; b < 8; ++b) {
                    st1(z + (size_t)(g * 8 + b) * 1024 + h0r,     zp0[b] + a0[b]);
                    st1(z + (size_t)(g * 8 + b) * 1024 + h0r + 1, zp1[b] + a1[b]);
                }
                if (t > 0) {
                    float* dst = kv_mat ? Vb : Kb;
                    #pragma unroll
                    for (int b = 0; b < 8; ++b)
                        st1(dst + ((size_t)(t - 1) * 8 + b) * 1024 + kv_h, akv[b] + kv_bias);
                }
            }
        }
        gsync(bar, ++bc, blk);

        // ===== Phase B: LN + gates + cell update (blocks 0..7, z staged in LDS) =====
        if (blk < 8) {
            const int b = blk;
            #pragma unroll
            for (int j = 0; j < 4; ++j) {
                const int idx = tid * 8 + j * 2;
                const int g2 = idx >> 10, hh = idx & 1023;
                *(float2*)(lds + S_HX + idx) = ld2(z + ((size_t)g2 * 8 + b) * 1024 + hh);
            }
            __syncthreads();
            const int gt = w >> 1, hf = w & 1;
            float s = 0.f, q = 0.f;
            #pragma unroll
            for (int j = 0; j < 8; ++j) {
                const float v = lds[S_HX + gt * 1024 + hf * 512 + j * 64 + l];
                s += v; q += v * v;
            }
            #pragma unroll
            for (int o = 1; o < 64; o <<= 1) { s += __shfl_xor(s, o); q += __shfl_xor(q, o); }
            if (l == 0) { lds[S_RED + w] = s; lds[S_RED + 8 + w] = q; }
            __syncthreads();
            float mean[4], rstd[4];
            #pragma unroll
            for (int g2 = 0; g2 < 4; ++g2) {
                const float ss = lds[S_RED + 2*g2] + lds[S_RED + 2*g2 + 1];
                const float qq = lds[S_RED + 8 + 2*g2] + lds[S_RED + 8 + 2*g2 + 1];
                const float m = ss * (1.f / 1024.f);
                mean[g2] = m;
                rstd[g2] = rsqrtf(qq * (1.f / 1024.f) - m * m + 1e-5f);
            }
            #pragma unroll
            for (int jj = 0; jj < 2; ++jj) {
                const int h = jj * 512 + tid;
                float zv[4];
                #pragma unroll
                for (int g2 = 0; g2 < 4; ++g2) {
                    const float v = lds[S_HX + g2 * 1024 + h];
                    zv[g2] = (v - mean[g2]) * rstd[g2] * lng[g2 * 1024 + h] + lnb[g2 * 1024 + h];
                }
                const float f  = 1.f / (1.f + __expf(-zv[0]));
                const float ii = 1.f / (1.f + __expf(-zv[1]));
                const float gg = tanhf(zv[2]);
                const float oo = 1.f / (1.f + __expf(-zv[3]));
                const float c  = f * lds[S_CX + h] + ii * gg;
                lds[S_CX + h] = c;
                st1(h0 + b * 1024 + h, oo * tanhf(c));
            }
        }
        gsync(bar, ++bc, blk);

        // ===== Phase CD: q-proj + attention (blocks 0..127, t>0) =====
        if (blk < 128 && t > 0) {
            const int b = blk >> 4, nh = blk & 15;
            *(float2*)(lds + S_HX + tid * 2) = ld2(h0 + b * 1024 + tid * 2);
            __syncthreads();
            {   // q-proj: 64 rows of Wq for this head; thread = (dh, ks8)
                const int dh = tid >> 3, ks = tid & 7;
                const float* wrow = Wq + (size_t)(nh * 64 + dh) * 1024;
                float qa = 0.f;
                #pragma unroll 8
                for (int j = 0; j < 32; ++j) {
                    const int k = j * 32 + ks * 4;
                    qa += dot4(*(const float4*)(wrow + k), *(const float4*)(lds + S_HX + k));
                }
                qa += __shfl_xor(qa, 1); qa += __shfl_xor(qa, 2); qa += __shfl_xor(qa, 4);
                if (ks == 0) lds[S_Q + dh] = (qa + bq[nh * 64 + dh]) * 0.125f;
            }
            __syncthreads();
            float sc = -1e30f;
            if (tid < t) {
                const float* kr = Kb + ((size_t)tid * 8 + b) * 1024 + nh * 64;
                float d = 0.f;
                #pragma unroll
                for (int j = 0; j < 32; ++j) {
                    const float2 k2 = ld2(kr + j * 2);
                    d += k2.x * lds[S_Q + j*2] + k2.y * lds[S_Q + j*2 + 1];
                }
                sc = d;
            }
            float mx = sc;
            #pragma unroll
            for (int o = 1; o < 64; o <<= 1) mx = fmaxf(mx, __shfl_xor(mx, o));
            if (l == 0) lds[S_RED + w] = mx;
            __syncthreads();
            mx = lds[S_RED];
            #pragma unroll
            for (int j = 1; j < 8; ++j) mx = fmaxf(mx, lds[S_RED + j]);
            const float p = (tid < t) ? __expf(sc - mx) : 0.f;
            if (tid < 256) lds[S_PS + tid] = p;
            float ps = p;
            #pragma unroll
            for (int o = 1; o < 64; o <<= 1) ps += __shfl_xor(ps, o);
            if (l == 0) lds[S_R2 + w] = ps;
            __syncthreads();
            float tot = lds[S_R2];
            #pragma unroll
            for (int j = 1; j < 8; ++j) tot += lds[S_R2 + j];
            const float inv = 1.f / tot;
            // PV: thread = (dh2 in 32 float2-cols, ss in 16 s-offsets)
            const int dh2 = tid & 31, ss = tid >> 5;
            float cax = 0.f, cay = 0.f;
            for (int s = ss; s < t; s += 16) {
                const float pp = lds[S_PS + s];
                const float2 v2 = ld2(Vb + ((size_t)s * 8 + b) * 1024 + nh * 64 + dh2 * 2);
                cax += pp * v2.x; cay += pp * v2.y;
            }
            *(float2*)(lds + S_CTXP + ss * 64 + dh2 * 2) = make_float2(cax, cay);
            __syncthreads();
            if (tid < 64) {
                float v = 0.f;
                #pragma unroll
                for (int j = 0; j < 16; ++j) v += lds[S_CTXP + j * 64 + tid];
                st1(ctx + b * 1024 + nh * 64 + tid, v * inv);
            }
        }
        gsync(bar, ++bc, blk);

        // ===== Phase E: out-proj + hx update + emit (all blocks; wave = batch) =====
        {
            const int b = w;
            float h0v[4];
            if (l == 0) {
                #pragma unroll
                for (int r = 0; r < 4; ++r) h0v[r] = ld1(h0 + b * 1024 + blk * 4 + r);
            }
            float o0 = 0.f, o1 = 0.f, o2 = 0.f, o3 = 0.f;
            if (t > 0) {
                const float* cb = ctx + b * 1024;
                #pragma unroll
                for (int i = 0; i < 4; ++i) {
                    const int k = i * 256 + l * 4;
                    const float4 c4 = ld4(cb + k);
                    const float4 w0 = *(const float4*)(Wo + (size_t)(blk*4+0) * 1024 + k);
                    const float4 w1 = *(const float4*)(Wo + (size_t)(blk*4+1) * 1024 + k);
                    const float4 w2 = *(const float4*)(Wo + (size_t)(blk*4+2) * 1024 + k);
                    const float4 w3 = *(const float4*)(Wo + (size_t)(blk*4+3) * 1024 + k);
                    o0 += dot4(w0, c4); o1 += dot4(w1, c4); o2 += dot4(w2, c4); o3 += dot4(w3, c4);
                }
                #pragma unroll
                for (int o = 1; o < 64; o <<= 1) {
                    o0 += __shfl_xor(o0, o); o1 += __shfl_xor(o1, o);
                    o2 += __shfl_xor(o2, o); o3 += __shfl_xor(o3, o);
                }
            }
            if (l == 0) {
                const float v0 = (t > 0) ? h0v[0] + o0 + bo0 : h0v[0];
                const float v1 = (t > 0) ? h0v[1] + o1 + bo1 : h0v[1];
                const float v2 = (t > 0) ? h0v[2] + o2 + bo2 : h0v[2];
                const float v3 = (t > 0) ? h0v[3] + o3 + bo3 : h0v[3];
                st1(hx + b * 1024 + blk*4 + 0, v0);
                st1(hx + b * 1024 + blk*4 + 1, v1);
                st1(hx + b * 1024 + blk*4 + 2, v2);
                st1(hx + b * 1024 + blk*4 + 3, v3);
                float* op = out + (size_t)t * 8192 + b * 1024 + blk * 4;
                op[0] = v0; op[1] = v1; op[2] = v2; op[3] = v3;
            }
        }
        gsync(bar, ++bc, blk);
    }

    // epilogue: final hx, cx
    if (blk < 8) {
        for (int h = tid; h < 1024; h += NTHR)
            out[2097152 + 8192 + blk * 1024 + h] = lds[S_CX + h];
    } else if (blk < 16) {
        const int b = blk - 8;
        for (int h = tid; h < 1024; h += NTHR)
            out[2097152 + b * 1024 + h] = ld1(hx + b * 1024 + h);
    }
}

extern "C" void kernel_launch(void* const* d_in, const int* in_sizes, int n_in,
                              void* d_out, int out_size, void* d_ws, size_t ws_size,
                              hipStream_t stream) {
    const float* x   = (const float*)d_in[0];
    const float* Wg  = (const float*)d_in[1];
    const float* bg  = (const float*)d_in[2];
    const float* lng = (const float*)d_in[3];
    const float* lnb = (const float*)d_in[4];
    const float* Wq  = (const float*)d_in[5];
    const float* Wk  = (const float*)d_in[6];
    const float* Wv  = (const float*)d_in[7];
    const float* bq  = (const float*)d_in[8];
    const float* bk  = (const float*)d_in[9];
    const float* bv  = (const float*)d_in[10];
    const float* Wo  = (const float*)d_in[11];
    const float* bo  = (const float*)d_in[12];
    float* out = (float*)d_out;
    float* ws  = (float*)d_ws;

    static int attr_set = 0;
    if (!attr_set) {
        hipFuncSetAttribute((const void*)qlstm_kernel,
                            hipFuncAttributeMaxDynamicSharedMemorySize, LDS_BYTES);
        attr_set = 1;
    }
    // zero barrier counters (graph-captured; deterministic per replay)
    hipMemsetAsync((char*)d_ws + (size_t)OFF_BAR * 4, 0, 4096, stream);

    void* args[] = { &x, &Wg, &bg, &lng, &lnb, &Wq, &Wk, &Wv,
                     &bq, &bk, &bv, &Wo, &bo, &out, &ws };
    hipLaunchCooperativeKernel((void*)qlstm_kernel, dim3(NBLK), dim3(NTHR),
                               args, LDS_BYTES, stream);
}

// Round 6
// 16435.849 us; speedup vs baseline: 1.1585x; 1.1585x over previous
//
#include <hip/hip_runtime.h>
#include <math.h>

#define NBLK 256
#define NTHR 512

// ws float offsets (cross-block data via device-scope sc1 ops)
#define OFF_HX  0               // [8][1024]
#define OFF_H0  8192            // [8][1024]
#define OFF_CTX 16384           // [8][1024]
#define OFF_Z   24576           // [4][8][1024]
#define OFF_KB  65536           // [256][8][1024]
#define OFF_VB  (OFF_KB + 2097152)
#define OFF_BAR (OFF_VB + 2097152)   // 1024 floats: 8 group ctrs (128B apart) + glob

// LDS float offsets
#define S_WG    0                // 32768 (128KB): 16 gate rows x 2048
#define S_STAGE 32768            // 4096: hx staging (A) / z staging (BCD)
#define S_CX    36864            // 1024: replicated cell state (blk<128)
#define S_H0L   37888            // 1024: local h0 (blk<128)
#define S_Q     38912            // 64
#define S_PS    38976            // 256
#define S_RED   39232            // 16
#define S_R2    39248            // 16
#define S_EH    39264            // 32
#define S_CTXP  39296            // 512
#define LDS_FLOATS 39808
#define LDS_BYTES  (LDS_FLOATS * 4)   // 159232 <= 163840

typedef unsigned long long u64;
union F2U { u64 u; float2 f; };

__device__ __forceinline__ float ld1(const float* p) {
    return __hip_atomic_load(const_cast<float*>(p), __ATOMIC_RELAXED, __HIP_MEMORY_SCOPE_AGENT);
}
__device__ __forceinline__ void st1(float* p, float v) {
    __hip_atomic_store(p, v, __ATOMIC_RELAXED, __HIP_MEMORY_SCOPE_AGENT);
}
__device__ __forceinline__ float2 ld2(const float* p) {
    F2U c; c.u = __hip_atomic_load(reinterpret_cast<u64*>(const_cast<float*>(p)),
                                   __ATOMIC_RELAXED, __HIP_MEMORY_SCOPE_AGENT);
    return c.f;
}
__device__ __forceinline__ float4 ld4(const float* p) {
    float2 a = ld2(p), b = ld2(p + 2);
    return make_float4(a.x, a.y, b.x, b.y);
}
__device__ __forceinline__ float dot4(const float4 a, const float4 b) {
    return a.x*b.x + a.y*b.y + a.z*b.z + a.w*b.w;
}

// Two-level monotonic relaxed-atomic grid barrier (8 groups of 32 blocks).
__device__ __forceinline__ void gsync(unsigned* barbase, unsigned bc, int blk) {
    __syncthreads();
    if (threadIdx.x == 0) {
        asm volatile("" ::: "memory");
        unsigned* grp  = barbase + ((blk >> 5) << 5);   // 128B apart
        unsigned* glob = barbase + 256;
        const unsigned a = __hip_atomic_fetch_add(grp, 1u, __ATOMIC_RELAXED, __HIP_MEMORY_SCOPE_AGENT);
        if (a == bc * 32u - 1u)
            __hip_atomic_fetch_add(glob, 1u, __ATOMIC_RELAXED, __HIP_MEMORY_SCOPE_AGENT);
        while (__hip_atomic_load(glob, __ATOMIC_RELAXED, __HIP_MEMORY_SCOPE_AGENT) < bc * 8u)
            __builtin_amdgcn_s_sleep(2);
        asm volatile("" ::: "memory");
    }
    __syncthreads();
}

__global__ __launch_bounds__(NTHR, 1)
void qlstm_kernel(const float* __restrict__ x,  const float* __restrict__ Wg,
                  const float* __restrict__ bg, const float* __restrict__ lng,
                  const float* __restrict__ lnb,const float* __restrict__ Wq,
                  const float* __restrict__ Wk, const float* __restrict__ Wv,
                  const float* __restrict__ bq, const float* __restrict__ bk,
                  const float* __restrict__ bv, const float* __restrict__ Wo,
                  const float* __restrict__ bo, float* __restrict__ out,
                  float* __restrict__ ws)
{
    extern __shared__ float lds[];
    const int blk = blockIdx.x, tid = threadIdx.x;
    const int w = tid >> 6, l = tid & 63;

    float* hx  = ws + OFF_HX;   float* h0g = ws + OFF_H0;
    float* ctx = ws + OFF_CTX;  float* z   = ws + OFF_Z;
    float* Kb  = ws + OFF_KB;   float* Vb  = ws + OFF_VB;
    unsigned* bar = (unsigned*)(ws + OFF_BAR);
    unsigned bc = 0;

    // ---- Wg slice (16 rows x 2048) -> LDS ----
    {
        const float* wsrc = Wg + (size_t)blk * 32768;
        #pragma unroll
        for (int j = 0; j < 16; ++j) {
            const int fi = j * 512 + tid;
            *(float4*)(lds + S_WG + fi * 4) = *(const float4*)(wsrc + fi * 4);
        }
    }
    // ---- K/V rows (1 per wave) in VGPRs ----
    const int kv_row = blk * 8 + w;
    const int kv_mat = kv_row >> 10, kv_h = kv_row & 1023;
    const float* kv_wrow = (kv_mat ? Wv : Wk) + (size_t)kv_h * 1024;
    float4 wkv[4];
    #pragma unroll
    for (int i = 0; i < 4; ++i) wkv[i] = *(const float4*)(kv_wrow + i * 256 + l * 4);
    const float kv_bias = (kv_mat ? bv : bk)[kv_h];
    // ---- gate rows (this block: gate g, rows h0r, h0r+1 per wave) ----
    const int g   = blk >> 6;
    const int h0r = (blk & 63) * 16 + 2 * w;
    const float bg0 = bg[g * 1024 + h0r], bg1 = bg[g * 1024 + h0r + 1];
    // ---- Wo rows blk*4..+3 in VGPRs (every wave holds all 4 rows) ----
    float4 wo0[4], wo1[4], wo2[4], wo3[4];
    #pragma unroll
    for (int i = 0; i < 4; ++i) {
        wo0[i] = *(const float4*)(Wo + (size_t)(blk*4+0) * 1024 + i * 256 + l * 4);
        wo1[i] = *(const float4*)(Wo + (size_t)(blk*4+1) * 1024 + i * 256 + l * 4);
        wo2[i] = *(const float4*)(Wo + (size_t)(blk*4+2) * 1024 + i * 256 + l * 4);
        wo3[i] = *(const float4*)(Wo + (size_t)(blk*4+3) * 1024 + i * 256 + l * 4);
    }
    const float bo0 = bo[blk*4+0], bo1 = bo[blk*4+1], bo2 = bo[blk*4+2], bo3 = bo[blk*4+3];
    // ---- attention-block preloads (blk<128): Wq head rows + LN params ----
    const int ab = blk >> 4, anh = blk & 15;
    const int qdh = tid >> 3, qks = tid & 7;
    float4 wq[32];
    float qbias = 0.f;
    float lnw0[4], lnw1[4], lnb0[4], lnb1[4];
    if (blk < 128) {
        const float* qrow = Wq + (size_t)(anh * 64 + qdh) * 1024;
        #pragma unroll
        for (int j = 0; j < 32; ++j) wq[j] = *(const float4*)(qrow + j * 32 + qks * 4);
        qbias = bq[anh * 64 + qdh];
        #pragma unroll
        for (int g2 = 0; g2 < 4; ++g2) {
            lnw0[g2] = lng[g2 * 1024 + tid];       lnb0[g2] = lnb[g2 * 1024 + tid];
            lnw1[g2] = lng[g2 * 1024 + 512 + tid]; lnb1[g2] = lnb[g2 * 1024 + 512 + tid];
        }
    }

    // ---- init: zero hx (sc1), zero replicated cx ----
    { const int idx = blk * NTHR + tid; if (idx < 8192) st1(hx + idx, 0.f); }
    if (blk < 128 && tid < 256) *(float4*)(lds + S_CX + tid * 4) = make_float4(0,0,0,0);
    gsync(bar, ++bc, blk);

    for (int t = 0; t < 256; ++t) {
        // ===== x-part of gate GEMV (no dependency on previous step) =====
        float a0[8], a1[8];
        {
            const float* xt = x + (size_t)t * 8192;
            #pragma unroll
            for (int b = 0; b < 8; ++b) { a0[b] = 0.f; a1[b] = 0.f; }
            #pragma unroll
            for (int i = 0; i < 4; ++i) {
                const int k = i * 256 + l * 4;
                const float4 w0 = *(const float4*)(lds + S_WG + (2*w)   * 2048 + k);
                const float4 w1 = *(const float4*)(lds + S_WG + (2*w+1) * 2048 + k);
                #pragma unroll
                for (int b = 0; b < 8; ++b) {
                    const float4 a = *(const float4*)(xt + b * 1024 + k);
                    a0[b] += dot4(w0, a); a1[b] += dot4(w1, a);
                }
            }
        }
        gsync(bar, ++bc, blk);   // hx(t-1) now visible

        // ===== Phase A: hx-part gate GEMV + KV proj =====
        {
            float akv[8];
            #pragma unroll
            for (int b = 0; b < 8; ++b) akv[b] = 0.f;
            #pragma unroll
            for (int c = 0; c < 2; ++c) {
                if (c) __syncthreads();
                #pragma unroll
                for (int j = 0; j < 4; ++j) {       // stage 2048 float2, 8B lane stride
                    const int idx = j * 512 + tid;
                    const int b = idx >> 8, off2 = idx & 255;
                    *(float2*)(lds + S_STAGE + idx * 2) = ld2(hx + b * 1024 + c * 512 + off2 * 2);
                }
                __syncthreads();
                #pragma unroll
                for (int ii = 0; ii < 2; ++ii) {
                    const int k = ii * 256 + l * 4;
                    const float4 w0 = *(const float4*)(lds + S_WG + (2*w)   * 2048 + 1024 + c * 512 + k);
                    const float4 w1 = *(const float4*)(lds + S_WG + (2*w+1) * 2048 + 1024 + c * 512 + k);
                    const float4 wk = wkv[c * 2 + ii];
                    #pragma unroll
                    for (int b = 0; b < 8; ++b) {
                        const float4 a = *(const float4*)(lds + S_STAGE + b * 512 + k);
                        a0[b] += dot4(w0, a); a1[b] += dot4(w1, a); akv[b] += dot4(wk, a);
                    }
                }
            }
            #pragma unroll
            for (int o = 1; o < 64; o <<= 1)
                #pragma unroll
                for (int b = 0; b < 8; ++b) {
                    a0[b]  += __shfl_xor(a0[b], o);
                    a1[b]  += __shfl_xor(a1[b], o);
                    akv[b] += __shfl_xor(akv[b], o);
                }
            if (l == 0) {
                #pragma unroll
                for (int b = 0; b < 8; ++b) {
                    st1(z + (size_t)(g * 8 + b) * 1024 + h0r,     a0[b] + bg0);
                    st1(z + (size_t)(g * 8 + b) * 1024 + h0r + 1, a1[b] + bg1);
                }
                if (t > 0) {
                    float* dst = kv_mat ? Vb : Kb;
                    #pragma unroll
                    for (int b = 0; b < 8; ++b)
                        st1(dst + ((size_t)(t - 1) * 8 + b) * 1024 + kv_h, akv[b] + kv_bias);
                }
            }
        }
        gsync(bar, ++bc, blk);

        // ===== Phase BCD: replicated LN+cell, q-proj, attention (blk<128) =====
        if (blk < 128) {
            const int b = ab;
            #pragma unroll
            for (int j = 0; j < 4; ++j) {           // stage z[4][1024], 8B lane stride
                const int idx = j * 512 + tid;
                const int g2 = idx >> 9, off2 = idx & 511;
                *(float2*)(lds + S_STAGE + idx * 2) = ld2(z + ((size_t)g2 * 8 + b) * 1024 + off2 * 2);
            }
            __syncthreads();
            const int gt = w >> 1, hf = w & 1;
            float s = 0.f, q2s = 0.f;
            #pragma unroll
            for (int j = 0; j < 8; ++j) {
                const float v = lds[S_STAGE + gt * 1024 + hf * 512 + j * 64 + l];
                s += v; q2s += v * v;
            }
            #pragma unroll
            for (int o = 1; o < 64; o <<= 1) { s += __shfl_xor(s, o); q2s += __shfl_xor(q2s, o); }
            if (l == 0) { lds[S_RED + w] = s; lds[S_R2 + w] = q2s; }
            __syncthreads();
            float mean[4], rstd[4];
            #pragma unroll
            for (int g2 = 0; g2 < 4; ++g2) {
                const float ss = lds[S_RED + 2*g2] + lds[S_RED + 2*g2 + 1];
                const float qq = lds[S_R2  + 2*g2] + lds[S_R2  + 2*g2 + 1];
                const float m = ss * (1.f / 1024.f);
                mean[g2] = m;
                rstd[g2] = rsqrtf(qq * (1.f / 1024.f) - m * m + 1e-5f);
            }
            {   // h = tid
                float zv[4];
                #pragma unroll
                for (int g2 = 0; g2 < 4; ++g2)
                    zv[g2] = (lds[S_STAGE + g2 * 1024 + tid] - mean[g2]) * rstd[g2] * lnw0[g2] + lnb0[g2];
                const float f  = 1.f / (1.f + __expf(-zv[0]));
                const float ii = 1.f / (1.f + __expf(-zv[1]));
                const float gg = tanhf(zv[2]);
                const float oo = 1.f / (1.f + __expf(-zv[3]));
                const float c  = f * lds[S_CX + tid] + ii * gg;
                lds[S_CX + tid] = c;
                const float ho = oo * tanhf(c);
                lds[S_H0L + tid] = ho;
                if (anh == 0) st1(h0g + b * 1024 + tid, ho);
            }
            {   // h = tid + 512
                float zv[4];
                #pragma unroll
                for (int g2 = 0; g2 < 4; ++g2)
                    zv[g2] = (lds[S_STAGE + g2 * 1024 + 512 + tid] - mean[g2]) * rstd[g2] * lnw1[g2] + lnb1[g2];
                const float f  = 1.f / (1.f + __expf(-zv[0]));
                const float ii = 1.f / (1.f + __expf(-zv[1]));
                const float gg = tanhf(zv[2]);
                const float oo = 1.f / (1.f + __expf(-zv[3]));
                const float c  = f * lds[S_CX + 512 + tid] + ii * gg;
                lds[S_CX + 512 + tid] = c;
                const float ho = oo * tanhf(c);
                lds[S_H0L + 512 + tid] = ho;
                if (anh == 0) st1(h0g + b * 1024 + 512 + tid, ho);
            }
            __syncthreads();
            {   // q-proj from VGPR Wq
                float qa = 0.f;
                #pragma unroll
                for (int j = 0; j < 32; ++j)
                    qa += dot4(wq[j], *(const float4*)(lds + S_H0L + j * 32 + qks * 4));
                qa += __shfl_xor(qa, 1); qa += __shfl_xor(qa, 2); qa += __shfl_xor(qa, 4);
                if (qks == 0) lds[S_Q + qdh] = (qa + qbias) * 0.125f;
            }
            __syncthreads();
            if (t > 0) {
                float sc = -1e30f;
                if (tid < t) {
                    const float* kr = Kb + ((size_t)tid * 8 + b) * 1024 + anh * 64;
                    float d = 0.f;
                    #pragma unroll
                    for (int j = 0; j < 32; ++j) {
                        const float2 k2 = ld2(kr + j * 2);
                        d += k2.x * lds[S_Q + j*2] + k2.y * lds[S_Q + j*2 + 1];
                    }
                    sc = d;
                }
                float mx = sc;
                #pragma unroll
                for (int o = 1; o < 64; o <<= 1) mx = fmaxf(mx, __shfl_xor(mx, o));
                if (l == 0) lds[S_RED + w] = mx;
                __syncthreads();
                mx = lds[S_RED];
                #pragma unroll
                for (int j = 1; j < 8; ++j) mx = fmaxf(mx, lds[S_RED + j]);
                const float p = (tid < t) ? __expf(sc - mx) : 0.f;
                if (tid < 256) lds[S_PS + tid] = p;
                float ps = p;
                #pragma unroll
                for (int o = 1; o < 64; o <<= 1) ps += __shfl_xor(ps, o);
                if (l == 0) lds[S_R2 + w] = ps;
                __syncthreads();
                float tot = lds[S_R2];
                #pragma unroll
                for (int j = 1; j < 8; ++j) tot += lds[S_R2 + j];
                const float inv = 1.f / tot;
                const int dh = tid & 63, ss = tid >> 6;
                float ca = 0.f;
                for (int s2 = ss; s2 < t; s2 += 8)
                    ca += lds[S_PS + s2] * ld1(Vb + ((size_t)s2 * 8 + b) * 1024 + anh * 64 + dh);
                lds[S_CTXP + ss * 64 + dh] = ca;
                __syncthreads();
                if (tid < 64) {
                    float v = 0.f;
                    #pragma unroll
                    for (int j = 0; j < 8; ++j) v += lds[S_CTXP + j * 64 + tid];
                    st1(ctx + b * 1024 + anh * 64 + tid, v * inv);
                }
            }
        }
        gsync(bar, ++bc, blk);

        // ===== Phase E: out-proj (VGPR Wo) + hx update + emit (all blocks) =====
        {
            if (tid < 32)
                lds[S_EH + tid] = ld1(h0g + (size_t)(tid >> 2) * 1024 + blk * 4 + (tid & 3));
            const int b = w;
            float o0 = 0.f, o1 = 0.f, o2 = 0.f, o3 = 0.f;
            if (t > 0) {
                const float* cb = ctx + b * 1024;
                #pragma unroll
                for (int i = 0; i < 4; ++i) {
                    const int k = i * 256 + l * 4;
                    const float4 c4 = ld4(cb + k);
                    o0 += dot4(wo0[i], c4); o1 += dot4(wo1[i], c4);
                    o2 += dot4(wo2[i], c4); o3 += dot4(wo3[i], c4);
                }
                #pragma unroll
                for (int o = 1; o < 64; o <<= 1) {
                    o0 += __shfl_xor(o0, o); o1 += __shfl_xor(o1, o);
                    o2 += __shfl_xor(o2, o); o3 += __shfl_xor(o3, o);
                }
            }
            __syncthreads();
            if (l == 0) {
                const float v0 = (t > 0) ? lds[S_EH + w*4 + 0] + o0 + bo0 : lds[S_EH + w*4 + 0];
                const float v1 = (t > 0) ? lds[S_EH + w*4 + 1] + o1 + bo1 : lds[S_EH + w*4 + 1];
                const float v2 = (t > 0) ? lds[S_EH + w*4 + 2] + o2 + bo2 : lds[S_EH + w*4 + 2];
                const float v3 = (t > 0) ? lds[S_EH + w*4 + 3] + o3 + bo3 : lds[S_EH + w*4 + 3];
                st1(hx + b * 1024 + blk*4 + 0, v0);
                st1(hx + b * 1024 + blk*4 + 1, v1);
                st1(hx + b * 1024 + blk*4 + 2, v2);
                st1(hx + b * 1024 + blk*4 + 3, v3);
                float* op = out + (size_t)t * 8192 + b * 1024 + blk * 4;
                op[0] = v0; op[1] = v1; op[2] = v2; op[3] = v3;
            }
        }
        // post-E barrier is the top-of-loop gsync of step t+1
    }
    gsync(bar, ++bc, blk);

    // epilogue: final hx, cx
    if (blk < 128 && (blk & 15) == 0) {
        const int b = blk >> 4;
        out[2097152 + 8192 + b * 1024 + tid]       = lds[S_CX + tid];
        out[2097152 + 8192 + b * 1024 + 512 + tid] = lds[S_CX + 512 + tid];
    } else if (blk >= 128 && blk < 136) {
        const int b = blk - 128;
        out[2097152 + b * 1024 + tid]       = ld1(hx + b * 1024 + tid);
        out[2097152 + b * 1024 + 512 + tid] = ld1(hx + b * 1024 + 512 + tid);
    }
}

extern "C" void kernel_launch(void* const* d_in, const int* in_sizes, int n_in,
                              void* d_out, int out_size, void* d_ws, size_t ws_size,
                              hipStream_t stream) {
    const float* x   = (const float*)d_in[0];
    const float* Wg  = (const float*)d_in[1];
    const float* bg  = (const float*)d_in[2];
    const float* lng = (const float*)d_in[3];
    const float* lnb = (const float*)d_in[4];
    const float* Wq  = (const float*)d_in[5];
    const float* Wk  = (const float*)d_in[6];
    const float* Wv  = (const float*)d_in[7];
    const float* bq  = (const float*)d_in[8];
    const float* bk  = (const float*)d_in[9];
    const float* bv  = (const float*)d_in[10];
    const float* Wo  = (const float*)d_in[11];
    const float* bo  = (const float*)d_in[12];
    float* out = (float*)d_out;
    float* ws  = (float*)d_ws;

    static int attr_set = 0;
    if (!attr_set) {
        hipFuncSetAttribute((const void*)qlstm_kernel,
                            hipFuncAttributeMaxDynamicSharedMemorySize, LDS_BYTES);
        attr_set = 1;
    }
    // zero barrier counters (graph-captured; deterministic per replay)
    hipMemsetAsync((char*)d_ws + (size_t)OFF_BAR * 4, 0, 4096, stream);

    void* args[] = { &x, &Wg, &bg, &lng, &lnb, &Wq, &Wk, &Wv,
                     &bq, &bk, &bv, &Wo, &bo, &out, &ws };
    hipLaunchCooperativeKernel((void*)qlstm_kernel, dim3(NBLK), dim3(NTHR),
                               args, LDS_BYTES, stream);
}

// Round 7
// 14796.251 us; speedup vs baseline: 1.2869x; 1.1108x over previous
//
#include <hip/hip_runtime.h>
#include <math.h>

#define NBLK 256
#define NTHR 512

// ws float offsets (cross-block data via device-scope sc1 ops)
#define OFF_HX    0               // [8][1024]
#define OFF_H0    8192            // [8][1024]
#define OFF_CTX   16384           // [8][1024]
#define OFF_Z     24576           // [4][8][1024]
#define OFF_Q     57344           // [8][1024]
#define OFF_KB    65536           // [256][8][1024]
#define OFF_VB    (OFF_KB + 2097152)
#define OFF_FLAGS (OFF_VB + 2097152)   // 256 slots x 16 uints + go word

// LDS float offsets
#define S_WG    0                // 32768 (128KB): 16 gate rows x 2048
#define S_STAGE 32768            // 4096: hx staging (A) / z staging (BC)
#define S_CX    36864            // 1024: replicated cell state for b=blk>>5
#define S_H0L   37888            // 1024: local h0 for b=blk>>5
#define S_Q     38912            // 64
#define S_PS    38976            // 256
#define S_RED   39232            // 16
#define S_R2    39248            // 16
#define S_EH    39264            // 32
#define S_CTXP  39296            // 512
#define LDS_FLOATS 39808
#define LDS_BYTES  (LDS_FLOATS * 4)   // 159232 <= 163840

typedef unsigned long long u64;
union F2U { u64 u; float2 f; };

__device__ __forceinline__ float ld1(const float* p) {
    return __hip_atomic_load(const_cast<float*>(p), __ATOMIC_RELAXED, __HIP_MEMORY_SCOPE_AGENT);
}
__device__ __forceinline__ void st1(float* p, float v) {
    __hip_atomic_store(p, v, __ATOMIC_RELAXED, __HIP_MEMORY_SCOPE_AGENT);
}
__device__ __forceinline__ unsigned ldu(const unsigned* p) {
    return __hip_atomic_load(const_cast<unsigned*>(p), __ATOMIC_RELAXED, __HIP_MEMORY_SCOPE_AGENT);
}
__device__ __forceinline__ void stu(unsigned* p, unsigned v) {
    __hip_atomic_store(p, v, __ATOMIC_RELAXED, __HIP_MEMORY_SCOPE_AGENT);
}
__device__ __forceinline__ float2 ld2(const float* p) {
    F2U c; c.u = __hip_atomic_load(reinterpret_cast<u64*>(const_cast<float*>(p)),
                                   __ATOMIC_RELAXED, __HIP_MEMORY_SCOPE_AGENT);
    return c.f;
}
__device__ __forceinline__ float4 ld4(const float* p) {
    float2 a = ld2(p), b = ld2(p + 2);
    return make_float4(a.x, a.y, b.x, b.y);
}
__device__ __forceinline__ float dot4(const float4 a, const float4 b) {
    return a.x*b.x + a.y*b.y + a.z*b.z + a.w*b.w;
}

// Flag-array grid barrier: parallel arrivals (own slot each), block 0 gathers
// with 256 watcher threads, releases via a single monotonic go word.
__device__ __forceinline__ void gsync(unsigned* flags, unsigned* go, unsigned bc, int blk) {
    __syncthreads();                     // drains each wave's vmcnt -> sc1 stores visible
    if (threadIdx.x == 0) stu(flags + blk * 16, bc);
    if (blk == 0) {
        if (threadIdx.x < 256)
            while (ldu(flags + threadIdx.x * 16) < bc) __builtin_amdgcn_s_sleep(2);
        __syncthreads();
        if (threadIdx.x == 0) stu(go, bc);
    }
    if (threadIdx.x == 0)
        while (ldu(go) < bc) __builtin_amdgcn_s_sleep(2);
    __syncthreads();
}

__global__ __launch_bounds__(NTHR, 1)
void qlstm_kernel(const float* __restrict__ x,  const float* __restrict__ Wg,
                  const float* __restrict__ bg, const float* __restrict__ lng,
                  const float* __restrict__ lnb,const float* __restrict__ Wq,
                  const float* __restrict__ Wk, const float* __restrict__ Wv,
                  const float* __restrict__ bq, const float* __restrict__ bk,
                  const float* __restrict__ bv, const float* __restrict__ Wo,
                  const float* __restrict__ bo, float* __restrict__ out,
                  float* __restrict__ ws)
{
    extern __shared__ float lds[];
    const int blk = blockIdx.x, tid = threadIdx.x;
    const int w = tid >> 6, l = tid & 63;

    float* hx  = ws + OFF_HX;   float* h0g = ws + OFF_H0;
    float* ctx = ws + OFF_CTX;  float* z   = ws + OFF_Z;
    float* qb  = ws + OFF_Q;
    float* Kb  = ws + OFF_KB;   float* Vb  = ws + OFF_VB;
    unsigned* flags = (unsigned*)(ws + OFF_FLAGS);
    unsigned* go    = flags + 4096;
    unsigned bc = 0;

    // ---- Wg slice (16 rows x 2048) -> LDS ----
    {
        const float* wsrc = Wg + (size_t)blk * 32768;
        #pragma unroll
        for (int j = 0; j < 16; ++j) {
            const int fi = j * 512 + tid;
            *(float4*)(lds + S_WG + fi * 4) = *(const float4*)(wsrc + fi * 4);
        }
    }
    // ---- K/V rows (1 per wave) in VGPRs ----
    const int kv_row = blk * 8 + w;
    const int kv_mat = kv_row >> 10, kv_h = kv_row & 1023;
    const float* kv_wrow = (kv_mat ? Wv : Wk) + (size_t)kv_h * 1024;
    float4 wkv[4];
    #pragma unroll
    for (int i = 0; i < 4; ++i) wkv[i] = *(const float4*)(kv_wrow + i * 256 + l * 4);
    const float kv_bias = (kv_mat ? bv : bk)[kv_h];
    // ---- gate rows (gate g, rows h0r, h0r+1 per wave) ----
    const int g   = blk >> 6;
    const int h0r = (blk & 63) * 16 + 2 * w;
    const float bg0 = bg[g * 1024 + h0r], bg1 = bg[g * 1024 + h0r + 1];
    // ---- q-proj: 32 rows/block, k-split 16 (64 wq floats per thread) ----
    const int qrow = (blk & 31) * 32 + (tid >> 4);   // 0..1023
    const int qks  = tid & 15;
    float4 wq4[16];
    #pragma unroll
    for (int i = 0; i < 16; ++i)
        wq4[i] = *(const float4*)(Wq + (size_t)qrow * 1024 + qks * 64 + i * 4);
    const float q_bias = bq[qrow];
    // ---- LN params for this thread's two h positions ----
    float lnw0[4], lnw1[4], lnb0[4], lnb1[4];
    #pragma unroll
    for (int g2 = 0; g2 < 4; ++g2) {
        lnw0[g2] = lng[g2 * 1024 + tid];       lnb0[g2] = lnb[g2 * 1024 + tid];
        lnw1[g2] = lng[g2 * 1024 + 512 + tid]; lnb1[g2] = lnb[g2 * 1024 + 512 + tid];
    }
    // ---- out-proj biases ----
    const float bo0 = bo[blk*4+0], bo1 = bo[blk*4+1], bo2 = bo[blk*4+2], bo3 = bo[blk*4+3];
    const int lnB = blk >> 5;   // batch owned for LN/q-proj replication

    // ---- init: zero hx (sc1), zero replicated cx ----
    { const int idx = blk * NTHR + tid; if (idx < 8192) st1(hx + idx, 0.f); }
    if (tid < 256) *(float4*)(lds + S_CX + tid * 4) = make_float4(0,0,0,0);
    gsync(flags, go, ++bc, blk);

    for (int t = 0; t < 256; ++t) {
        // ===== x-part of gate GEMV (no dependency on previous step) =====
        float a0[8], a1[8];
        {
            const float* xt = x + (size_t)t * 8192;
            #pragma unroll
            for (int b = 0; b < 8; ++b) { a0[b] = 0.f; a1[b] = 0.f; }
            #pragma unroll
            for (int i = 0; i < 4; ++i) {
                const int k = i * 256 + l * 4;
                const float4 w0 = *(const float4*)(lds + S_WG + (2*w)   * 2048 + k);
                const float4 w1 = *(const float4*)(lds + S_WG + (2*w+1) * 2048 + k);
                #pragma unroll
                for (int b = 0; b < 8; ++b) {
                    const float4 a = *(const float4*)(xt + b * 1024 + k);
                    a0[b] += dot4(w0, a); a1[b] += dot4(w1, a);
                }
            }
        }
        gsync(flags, go, ++bc, blk);   // hx(t-1) now visible

        // ===== Phase A: hx-part gate GEMV + KV proj =====
        {
            float akv[8];
            #pragma unroll
            for (int b = 0; b < 8; ++b) akv[b] = 0.f;
            #pragma unroll
            for (int c = 0; c < 2; ++c) {
                if (c) __syncthreads();
                #pragma unroll
                for (int j = 0; j < 4; ++j) {       // stage 2048 float2, 8B lane stride
                    const int idx = j * 512 + tid;
                    const int b = idx >> 8, off2 = idx & 255;
                    *(float2*)(lds + S_STAGE + idx * 2) = ld2(hx + b * 1024 + c * 512 + off2 * 2);
                }
                __syncthreads();
                #pragma unroll
                for (int ii = 0; ii < 2; ++ii) {
                    const int k = ii * 256 + l * 4;
                    const float4 w0 = *(const float4*)(lds + S_WG + (2*w)   * 2048 + 1024 + c * 512 + k);
                    const float4 w1 = *(const float4*)(lds + S_WG + (2*w+1) * 2048 + 1024 + c * 512 + k);
                    const float4 wk = wkv[c * 2 + ii];
                    #pragma unroll
                    for (int b = 0; b < 8; ++b) {
                        const float4 a = *(const float4*)(lds + S_STAGE + b * 512 + k);
                        a0[b] += dot4(w0, a); a1[b] += dot4(w1, a); akv[b] += dot4(wk, a);
                    }
                }
            }
            #pragma unroll
            for (int o = 1; o < 64; o <<= 1)
                #pragma unroll
                for (int b = 0; b < 8; ++b) {
                    a0[b]  += __shfl_xor(a0[b], o);
                    a1[b]  += __shfl_xor(a1[b], o);
                    akv[b] += __shfl_xor(akv[b], o);
                }
            if (l == 0) {
                #pragma unroll
                for (int b = 0; b < 8; ++b) {
                    st1(z + (size_t)(g * 8 + b) * 1024 + h0r,     a0[b] + bg0);
                    st1(z + (size_t)(g * 8 + b) * 1024 + h0r + 1, a1[b] + bg1);
                }
                if (t > 0) {
                    float* dst = kv_mat ? Vb : Kb;
                    #pragma unroll
                    for (int b = 0; b < 8; ++b)
                        st1(dst + ((size_t)(t - 1) * 8 + b) * 1024 + kv_h, akv[b] + kv_bias);
                }
            }
        }
        gsync(flags, go, ++bc, blk);

        // ===== Phase BC: replicated LN+cell (b=lnB) + q-proj rows (all blocks) =====
        {
            const int b = lnB;
            #pragma unroll
            for (int j = 0; j < 4; ++j) {           // stage z[4][b][1024], 8B lane stride
                const int idx = j * 512 + tid;
                const int g2 = idx >> 9, off2 = idx & 511;
                *(float2*)(lds + S_STAGE + idx * 2) = ld2(z + ((size_t)g2 * 8 + b) * 1024 + off2 * 2);
            }
            __syncthreads();
            const int gt = w >> 1, hf = w & 1;
            float s = 0.f, q2s = 0.f;
            #pragma unroll
            for (int j = 0; j < 8; ++j) {
                const float v = lds[S_STAGE + gt * 1024 + hf * 512 + j * 64 + l];
                s += v; q2s += v * v;
            }
            #pragma unroll
            for (int o = 1; o < 64; o <<= 1) { s += __shfl_xor(s, o); q2s += __shfl_xor(q2s, o); }
            if (l == 0) { lds[S_RED + w] = s; lds[S_R2 + w] = q2s; }
            __syncthreads();
            float mean[4], rstd[4];
            #pragma unroll
            for (int g2 = 0; g2 < 4; ++g2) {
                const float ss = lds[S_RED + 2*g2] + lds[S_RED + 2*g2 + 1];
                const float qq = lds[S_R2  + 2*g2] + lds[S_R2  + 2*g2 + 1];
                const float m = ss * (1.f / 1024.f);
                mean[g2] = m;
                rstd[g2] = rsqrtf(qq * (1.f / 1024.f) - m * m + 1e-5f);
            }
            {   // h = tid
                float zv[4];
                #pragma unroll
                for (int g2 = 0; g2 < 4; ++g2)
                    zv[g2] = (lds[S_STAGE + g2 * 1024 + tid] - mean[g2]) * rstd[g2] * lnw0[g2] + lnb0[g2];
                const float f  = 1.f / (1.f + __expf(-zv[0]));
                const float ii = 1.f / (1.f + __expf(-zv[1]));
                const float gg = tanhf(zv[2]);
                const float oo = 1.f / (1.f + __expf(-zv[3]));
                const float c  = f * lds[S_CX + tid] + ii * gg;
                lds[S_CX + tid] = c;
                const float ho = oo * tanhf(c);
                lds[S_H0L + tid] = ho;
                if ((blk & 31) == 0) st1(h0g + b * 1024 + tid, ho);
            }
            {   // h = tid + 512
                float zv[4];
                #pragma unroll
                for (int g2 = 0; g2 < 4; ++g2)
                    zv[g2] = (lds[S_STAGE + g2 * 1024 + 512 + tid] - mean[g2]) * rstd[g2] * lnw1[g2] + lnb1[g2];
                const float f  = 1.f / (1.f + __expf(-zv[0]));
                const float ii = 1.f / (1.f + __expf(-zv[1]));
                const float gg = tanhf(zv[2]);
                const float oo = 1.f / (1.f + __expf(-zv[3]));
                const float c  = f * lds[S_CX + 512 + tid] + ii * gg;
                lds[S_CX + 512 + tid] = c;
                const float ho = oo * tanhf(c);
                lds[S_H0L + 512 + tid] = ho;
                if ((blk & 31) == 0) st1(h0g + b * 1024 + 512 + tid, ho);
            }
            __syncthreads();
            {   // q-proj: row qrow, k-chunk qks (VGPR weights, LDS h0)
                float qa = 0.f;
                #pragma unroll
                for (int i = 0; i < 16; ++i)
                    qa += dot4(wq4[i], *(const float4*)(lds + S_H0L + qks * 64 + i * 4));
                qa += __shfl_xor(qa, 1); qa += __shfl_xor(qa, 2);
                qa += __shfl_xor(qa, 4); qa += __shfl_xor(qa, 8);
                if (qks == 0) st1(qb + b * 1024 + qrow, (qa + q_bias) * 0.125f);
            }
        }
        gsync(flags, go, ++bc, blk);

        // ===== Phase D: attention (blocks 0..127, t>0) =====
        if (blk < 128 && t > 0) {
            const int b = blk >> 4, anh = blk & 15;
            if (tid < 32) *(float2*)(lds + S_Q + tid * 2) = ld2(qb + b * 1024 + anh * 64 + tid * 2);
            __syncthreads();
            float sc = -1e30f;
            if (tid < t) {
                const float* kr = Kb + ((size_t)tid * 8 + b) * 1024 + anh * 64;
                float d = 0.f;
                #pragma unroll
                for (int j = 0; j < 32; ++j) {
                    const float2 k2 = ld2(kr + j * 2);
                    d += k2.x * lds[S_Q + j*2] + k2.y * lds[S_Q + j*2 + 1];
                }
                sc = d;
            }
            float mx = sc;
            #pragma unroll
            for (int o = 1; o < 64; o <<= 1) mx = fmaxf(mx, __shfl_xor(mx, o));
            if (l == 0) lds[S_RED + w] = mx;
            __syncthreads();
            mx = lds[S_RED];
            #pragma unroll
            for (int j = 1; j < 8; ++j) mx = fmaxf(mx, lds[S_RED + j]);
            const float p = (tid < t) ? __expf(sc - mx) : 0.f;
            if (tid < 256) lds[S_PS + tid] = p;
            float ps = p;
            #pragma unroll
            for (int o = 1; o < 64; o <<= 1) ps += __shfl_xor(ps, o);
            if (l == 0) lds[S_R2 + w] = ps;
            __syncthreads();
            float tot = lds[S_R2];
            #pragma unroll
            for (int j = 1; j < 8; ++j) tot += lds[S_R2 + j];
            const float inv = 1.f / tot;
            const int dh = tid & 63, ss = tid >> 6;
            float ca = 0.f;
            for (int s2 = ss; s2 < t; s2 += 8)
                ca += lds[S_PS + s2] * ld1(Vb + ((size_t)s2 * 8 + b) * 1024 + anh * 64 + dh);
            lds[S_CTXP + ss * 64 + dh] = ca;
            __syncthreads();
            if (tid < 64) {
                float v = 0.f;
                #pragma unroll
                for (int j = 0; j < 8; ++j) v += lds[S_CTXP + j * 64 + tid];
                st1(ctx + b * 1024 + anh * 64 + tid, v * inv);
            }
        }
        gsync(flags, go, ++bc, blk);

        // ===== Phase E: out-proj (cached Wo, 4 rows) + hx update + emit =====
        {
            if (tid < 32)
                lds[S_EH + tid] = ld1(h0g + (size_t)(tid >> 2) * 1024 + blk * 4 + (tid & 3));
            const int b = w;
            float o0 = 0.f, o1 = 0.f, o2 = 0.f, o3 = 0.f;
            if (t > 0) {
                const float* cb = ctx + b * 1024;
                #pragma unroll
                for (int i = 0; i < 4; ++i) {
                    const int k = i * 256 + l * 4;
                    const float4 c4 = ld4(cb + k);
                    o0 += dot4(*(const float4*)(Wo + (size_t)(blk*4+0) * 1024 + k), c4);
                    o1 += dot4(*(const float4*)(Wo + (size_t)(blk*4+1) * 1024 + k), c4);
                    o2 += dot4(*(const float4*)(Wo + (size_t)(blk*4+2) * 1024 + k), c4);
                    o3 += dot4(*(const float4*)(Wo + (size_t)(blk*4+3) * 1024 + k), c4);
                }
                #pragma unroll
                for (int o = 1; o < 64; o <<= 1) {
                    o0 += __shfl_xor(o0, o); o1 += __shfl_xor(o1, o);
                    o2 += __shfl_xor(o2, o); o3 += __shfl_xor(o3, o);
                }
            }
            __syncthreads();
            if (l == 0) {
                const float v0 = (t > 0) ? lds[S_EH + w*4 + 0] + o0 + bo0 : lds[S_EH + w*4 + 0];
                const float v1 = (t > 0) ? lds[S_EH + w*4 + 1] + o1 + bo1 : lds[S_EH + w*4 + 1];
                const float v2 = (t > 0) ? lds[S_EH + w*4 + 2] + o2 + bo2 : lds[S_EH + w*4 + 2];
                const float v3 = (t > 0) ? lds[S_EH + w*4 + 3] + o3 + bo3 : lds[S_EH + w*4 + 3];
                st1(hx + b * 1024 + blk*4 + 0, v0);
                st1(hx + b * 1024 + blk*4 + 1, v1);
                st1(hx + b * 1024 + blk*4 + 2, v2);
                st1(hx + b * 1024 + blk*4 + 3, v3);
                float* op = out + (size_t)t * 8192 + b * 1024 + blk * 4;
                op[0] = v0; op[1] = v1; op[2] = v2; op[3] = v3;
            }
        }
        // post-E barrier is the top-of-loop gsync of step t+1
    }
    gsync(flags, go, ++bc, blk);

    // epilogue: final cx (from replicas) and hx
    if ((blk & 31) == 0) {
        const int b = blk >> 5;
        out[2097152 + 8192 + b * 1024 + tid]       = lds[S_CX + tid];
        out[2097152 + 8192 + b * 1024 + 512 + tid] = lds[S_CX + 512 + tid];
    }
    if (blk >= 136 && blk < 144) {
        const int b = blk - 136;
        out[2097152 + b * 1024 + tid]       = ld1(hx + b * 1024 + tid);
        out[2097152 + b * 1024 + 512 + tid] = ld1(hx + b * 1024 + 512 + tid);
    }
}

extern "C" void kernel_launch(void* const* d_in, const int* in_sizes, int n_in,
                              void* d_out, int out_size, void* d_ws, size_t ws_size,
                              hipStream_t stream) {
    const float* x   = (const float*)d_in[0];
    const float* Wg  = (const float*)d_in[1];
    const float* bg  = (const float*)d_in[2];
    const float* lng = (const float*)d_in[3];
    const float* lnb = (const float*)d_in[4];
    const float* Wq  = (const float*)d_in[5];
    const float* Wk  = (const float*)d_in[6];
    const float* Wv  = (const float*)d_in[7];
    const float* bq  = (const float*)d_in[8];
    const float* bk  = (const float*)d_in[9];
    const float* bv  = (const float*)d_in[10];
    const float* Wo  = (const float*)d_in[11];
    const float* bo  = (const float*)d_in[12];
    float* out = (float*)d_out;
    float* ws  = (float*)d_ws;

    static int attr_set = 0;
    if (!attr_set) {
        hipFuncSetAttribute((const void*)qlstm_kernel,
                            hipFuncAttributeMaxDynamicSharedMemorySize, LDS_BYTES);
        attr_set = 1;
    }
    // zero barrier flags + go (graph-captured; deterministic per replay)
    hipMemsetAsync((char*)d_ws + (size_t)OFF_FLAGS * 4, 0, (4096 + 16) * 4, stream);

    void* args[] = { &x, &Wg, &bg, &lng, &lnb, &Wq, &Wk, &Wv,
                     &bq, &bk, &bv, &Wo, &bo, &out, &ws };
    hipLaunchCooperativeKernel((void*)qlstm_kernel, dim3(NBLK), dim3(NTHR),
                               args, LDS_BYTES, stream);
}

// Round 8
// 14367.793 us; speedup vs baseline: 1.3253x; 1.0298x over previous
//
#include <hip/hip_runtime.h>
#include <math.h>

#define NBLK 256
#define NTHR 512

// ws float offsets (cross-block data via device-scope sc1 ops)
#define OFF_HX    0               // [8][1024]
#define OFF_H0    8192            // [8][1024]
#define OFF_CTX   16384           // [8][1024]
#define OFF_Z     24576           // [4][8][1024]
#define OFF_Q     57344           // [8][1024]
#define OFF_KB    65536           // [256][8][1024]
#define OFF_VB    (OFF_KB + 2097152)
#define OFF_FLAGS (OFF_VB + 2097152)   // 256 arrive slots (16u apart) + 8 go lines

// LDS float offsets
#define S_WG    0                // 32768 (128KB): 16 gate rows x 2048
#define S_STAGE 32768            // 4096: hx staging (A) / z staging (BC) / PV partials (D)
#define S_CX    36864            // 1024: replicated cell state for b=blk>>5
#define S_H0L   37888            // 1024: local h0 for b=blk>>5
#define S_Q     38912            // 64
#define S_PS    38976            // 256: q partials (BC) / softmax p (D)
#define S_RED   39232            // 16
#define S_R2    39248            // 16
#define S_EH    39264            // 32
#define LDS_FLOATS 39296
#define LDS_BYTES  (LDS_FLOATS * 4)

typedef unsigned long long u64;
union F2U { u64 u; float2 f; };

__device__ __forceinline__ float ld1(const float* p) {
    return __hip_atomic_load(const_cast<float*>(p), __ATOMIC_RELAXED, __HIP_MEMORY_SCOPE_AGENT);
}
__device__ __forceinline__ void st1(float* p, float v) {
    __hip_atomic_store(p, v, __ATOMIC_RELAXED, __HIP_MEMORY_SCOPE_AGENT);
}
__device__ __forceinline__ unsigned ldu(const unsigned* p) {
    return __hip_atomic_load(const_cast<unsigned*>(p), __ATOMIC_RELAXED, __HIP_MEMORY_SCOPE_AGENT);
}
__device__ __forceinline__ void stu(unsigned* p, unsigned v) {
    __hip_atomic_store(p, v, __ATOMIC_RELAXED, __HIP_MEMORY_SCOPE_AGENT);
}
__device__ __forceinline__ float2 ld2(const float* p) {
    F2U c; c.u = __hip_atomic_load(reinterpret_cast<u64*>(const_cast<float*>(p)),
                                   __ATOMIC_RELAXED, __HIP_MEMORY_SCOPE_AGENT);
    return c.f;
}
__device__ __forceinline__ float4 ld4(const float* p) {
    float2 a = ld2(p), b = ld2(p + 2);
    return make_float4(a.x, a.y, b.x, b.y);
}
__device__ __forceinline__ float dot4(const float4 a, const float4 b) {
    return a.x*b.x + a.y*b.y + a.z*b.z + a.w*b.w;
}

// Flag-array grid barrier: parallel arrivals, block-0 watchers, release via
// 8 per-group go lines (32 pollers each — low contention).
__device__ __forceinline__ void gsync(unsigned* flags, unsigned* golines,
                                      unsigned bc, int blk) {
    __syncthreads();                 // drains vmcnt -> sc1 stores visible
    if (threadIdx.x == 0) stu(flags + blk * 16, bc);
    if (blk == 0) {
        if (threadIdx.x < 256)
            while (ldu(flags + threadIdx.x * 16) < bc) __builtin_amdgcn_s_sleep(1);
        __syncthreads();
        if (threadIdx.x < 8) stu(golines + threadIdx.x * 16, bc);
    } else {
        if (threadIdx.x == 0)
            while (ldu(golines + (blk >> 5) * 16) < bc) __builtin_amdgcn_s_sleep(1);
    }
    __syncthreads();
}

__global__ __launch_bounds__(NTHR, 1)
void qlstm_kernel(const float* __restrict__ x,  const float* __restrict__ Wg,
                  const float* __restrict__ bg, const float* __restrict__ lng,
                  const float* __restrict__ lnb,const float* __restrict__ Wq,
                  const float* __restrict__ Wk, const float* __restrict__ Wv,
                  const float* __restrict__ bq, const float* __restrict__ bk,
                  const float* __restrict__ bv, const float* __restrict__ Wo,
                  const float* __restrict__ bo, float* __restrict__ out,
                  float* __restrict__ ws)
{
    extern __shared__ float lds[];
    const int blk = blockIdx.x, tid = threadIdx.x;
    const int w = tid >> 6, l = tid & 63;

    float* hx  = ws + OFF_HX;   float* h0g = ws + OFF_H0;
    float* ctx = ws + OFF_CTX;  float* z   = ws + OFF_Z;
    float* qb  = ws + OFF_Q;
    float* Kb  = ws + OFF_KB;   float* Vb  = ws + OFF_VB;
    unsigned* flags   = (unsigned*)(ws + OFF_FLAGS);
    unsigned* golines = flags + 4096;
    unsigned bc = 0;

    // ---- Wg slice (16 rows x 2048) -> LDS ----
    {
        const float* wsrc = Wg + (size_t)blk * 32768;
        #pragma unroll
        for (int j = 0; j < 16; ++j) {
            const int fi = j * 512 + tid;
            *(float4*)(lds + S_WG + fi * 4) = *(const float4*)(wsrc + fi * 4);
        }
    }
    // ---- K/V rows (1 per wave) in VGPRs ----
    const int kv_row = blk * 8 + w;
    const int kv_mat = kv_row >> 10, kv_h = kv_row & 1023;
    const float* kv_wrow = (kv_mat ? Wv : Wk) + (size_t)kv_h * 1024;
    float4 wkv[4];
    #pragma unroll
    for (int i = 0; i < 4; ++i) wkv[i] = *(const float4*)(kv_wrow + i * 256 + l * 4);
    const float kv_bias = (kv_mat ? bv : bk)[kv_h];
    // ---- gate rows (gate g, rows h0r, h0r+1 per wave) ----
    const int g   = blk >> 6;
    const int h0r = (blk & 63) * 16 + 2 * w;
    const float bg0 = bg[g * 1024 + h0r], bg1 = bg[g * 1024 + h0r + 1];
    // ---- q-proj: 32 rows/block; thread = (r = tid&31, ks = tid>>5) ----
    const int qr  = tid & 31, qks = tid >> 5;
    const int qrow = (blk & 31) * 32 + qr;           // 0..1023
    float4 wq4[16];
    #pragma unroll
    for (int i = 0; i < 16; ++i)
        wq4[i] = *(const float4*)(Wq + (size_t)qrow * 1024 + qks * 64 + i * 4);
    const float q_bias_r = bq[(blk & 31) * 32 + (tid & 31)];
    // ---- LN params for this thread's two h positions ----
    float lnw0[4], lnw1[4], lnb0[4], lnb1[4];
    #pragma unroll
    for (int g2 = 0; g2 < 4; ++g2) {
        lnw0[g2] = lng[g2 * 1024 + tid];       lnb0[g2] = lnb[g2 * 1024 + tid];
        lnw1[g2] = lng[g2 * 1024 + 512 + tid]; lnb1[g2] = lnb[g2 * 1024 + 512 + tid];
    }
    // ---- out-proj biases ----
    const float bo0 = bo[blk*4+0], bo1 = bo[blk*4+1], bo2 = bo[blk*4+2], bo3 = bo[blk*4+3];
    const int lnB = blk >> 5;   // batch owned for LN/cell/q replication

    // ---- init: zero hx (sc1), zero replicated cx ----
    { const int idx = blk * NTHR + tid; if (idx < 8192) st1(hx + idx, 0.f); }
    if (tid < 256) *(float4*)(lds + S_CX + tid * 4) = make_float4(0,0,0,0);
    gsync(flags, golines, ++bc, blk);

    for (int t = 0; t < 256; ++t) {
        // ===== x-part of gate GEMV (no dependency on previous step) =====
        float a0[8], a1[8];
        {
            const float* xt = x + (size_t)t * 8192;
            #pragma unroll
            for (int b = 0; b < 8; ++b) { a0[b] = 0.f; a1[b] = 0.f; }
            #pragma unroll
            for (int i = 0; i < 4; ++i) {
                const int k = i * 256 + l * 4;
                const float4 w0 = *(const float4*)(lds + S_WG + (2*w)   * 2048 + k);
                const float4 w1 = *(const float4*)(lds + S_WG + (2*w+1) * 2048 + k);
                #pragma unroll
                for (int b = 0; b < 8; ++b) {
                    const float4 a = *(const float4*)(xt + b * 1024 + k);
                    a0[b] += dot4(w0, a); a1[b] += dot4(w1, a);
                }
            }
        }
        gsync(flags, golines, ++bc, blk);   // hx(t-1) now visible

        // ===== Phase A: hx-part gate GEMV + KV proj (both chunks reg-prefetched) =====
        {
            float akv[8];
            #pragma unroll
            for (int b = 0; b < 8; ++b) akv[b] = 0.f;
            float2 hreg[8];
            #pragma unroll
            for (int c = 0; c < 2; ++c)
                #pragma unroll
                for (int j = 0; j < 4; ++j) {
                    const int idx = j * 512 + tid;
                    const int b = idx >> 8, off2 = idx & 255;
                    hreg[c * 4 + j] = ld2(hx + b * 1024 + c * 512 + off2 * 2);
                }
            #pragma unroll
            for (int c = 0; c < 2; ++c) {
                if (c) __syncthreads();
                #pragma unroll
                for (int j = 0; j < 4; ++j)
                    *(float2*)(lds + S_STAGE + (j * 512 + tid) * 2) = hreg[c * 4 + j];
                __syncthreads();
                #pragma unroll
                for (int ii = 0; ii < 2; ++ii) {
                    const int k = ii * 256 + l * 4;
                    const float4 w0 = *(const float4*)(lds + S_WG + (2*w)   * 2048 + 1024 + c * 512 + k);
                    const float4 w1 = *(const float4*)(lds + S_WG + (2*w+1) * 2048 + 1024 + c * 512 + k);
                    const float4 wk = wkv[c * 2 + ii];
                    #pragma unroll
                    for (int b = 0; b < 8; ++b) {
                        const float4 a = *(const float4*)(lds + S_STAGE + b * 512 + k);
                        a0[b] += dot4(w0, a); a1[b] += dot4(w1, a); akv[b] += dot4(wk, a);
                    }
                }
            }
            #pragma unroll
            for (int o = 1; o < 64; o <<= 1)
                #pragma unroll
                for (int b = 0; b < 8; ++b) {
                    a0[b]  += __shfl_xor(a0[b], o);
                    a1[b]  += __shfl_xor(a1[b], o);
                    akv[b] += __shfl_xor(akv[b], o);
                }
            if (l == 0) {
                #pragma unroll
                for (int b = 0; b < 8; ++b) {
                    st1(z + (size_t)(g * 8 + b) * 1024 + h0r,     a0[b] + bg0);
                    st1(z + (size_t)(g * 8 + b) * 1024 + h0r + 1, a1[b] + bg1);
                }
                if (t > 0) {
                    float* dst = kv_mat ? Vb : Kb;
                    #pragma unroll
                    for (int b = 0; b < 8; ++b)
                        st1(dst + ((size_t)(t - 1) * 8 + b) * 1024 + kv_h, akv[b] + kv_bias);
                }
            }
        }
        gsync(flags, golines, ++bc, blk);

        // ===== Phase BC: replicated LN+cell (b=lnB) + q-proj rows (all blocks) =====
        {
            const int b = lnB;
            #pragma unroll
            for (int j = 0; j < 4; ++j) {           // stage z[4][b][1024]
                const int idx = j * 512 + tid;
                const int g2 = idx >> 9, off2 = idx & 511;
                *(float2*)(lds + S_STAGE + idx * 2) = ld2(z + ((size_t)g2 * 8 + b) * 1024 + off2 * 2);
            }
            __syncthreads();
            const int gt = w >> 1, hf = w & 1;
            float s = 0.f, q2s = 0.f;
            #pragma unroll
            for (int j = 0; j < 8; ++j) {
                const float v = lds[S_STAGE + gt * 1024 + hf * 512 + j * 64 + l];
                s += v; q2s += v * v;
            }
            #pragma unroll
            for (int o = 1; o < 64; o <<= 1) { s += __shfl_xor(s, o); q2s += __shfl_xor(q2s, o); }
            if (l == 0) { lds[S_RED + w] = s; lds[S_R2 + w] = q2s; }
            __syncthreads();
            float mean[4], rstd[4];
            #pragma unroll
            for (int g2 = 0; g2 < 4; ++g2) {
                const float ss = lds[S_RED + 2*g2] + lds[S_RED + 2*g2 + 1];
                const float qq = lds[S_R2  + 2*g2] + lds[S_R2  + 2*g2 + 1];
                const float m = ss * (1.f / 1024.f);
                mean[g2] = m;
                rstd[g2] = rsqrtf(qq * (1.f / 1024.f) - m * m + 1e-5f);
            }
            {   // h = tid
                float zv[4];
                #pragma unroll
                for (int g2 = 0; g2 < 4; ++g2)
                    zv[g2] = (lds[S_STAGE + g2 * 1024 + tid] - mean[g2]) * rstd[g2] * lnw0[g2] + lnb0[g2];
                const float f  = 1.f / (1.f + __expf(-zv[0]));
                const float ii = 1.f / (1.f + __expf(-zv[1]));
                const float gg = tanhf(zv[2]);
                const float oo = 1.f / (1.f + __expf(-zv[3]));
                const float c  = f * lds[S_CX + tid] + ii * gg;
                lds[S_CX + tid] = c;
                const float ho = oo * tanhf(c);
                lds[S_H0L + tid] = ho;
                if ((blk & 31) == 0) st1(h0g + b * 1024 + tid, ho);
            }
            {   // h = tid + 512
                float zv[4];
                #pragma unroll
                for (int g2 = 0; g2 < 4; ++g2)
                    zv[g2] = (lds[S_STAGE + g2 * 1024 + 512 + tid] - mean[g2]) * rstd[g2] * lnw1[g2] + lnb1[g2];
                const float f  = 1.f / (1.f + __expf(-zv[0]));
                const float ii = 1.f / (1.f + __expf(-zv[1]));
                const float gg = tanhf(zv[2]);
                const float oo = 1.f / (1.f + __expf(-zv[3]));
                const float c  = f * lds[S_CX + 512 + tid] + ii * gg;
                lds[S_CX + 512 + tid] = c;
                const float ho = oo * tanhf(c);
                lds[S_H0L + 512 + tid] = ho;
                if ((blk & 31) == 0) st1(h0g + b * 1024 + 512 + tid, ho);
            }
            __syncthreads();
            {   // q-proj: broadcast LDS reads (conflict-free), 2-stage reduce
                float qa = 0.f;
                #pragma unroll
                for (int i = 0; i < 16; ++i)
                    qa += dot4(wq4[i], *(const float4*)(lds + S_H0L + qks * 64 + i * 4));
                qa += __shfl_xor(qa, 32);
                if (l < 32) lds[S_PS + w * 32 + l] = qa;
                __syncthreads();
                if (tid < 32) {
                    float qs = 0.f;
                    #pragma unroll
                    for (int j = 0; j < 8; ++j) qs += lds[S_PS + j * 32 + tid];
                    st1(qb + b * 1024 + (blk & 31) * 32 + tid, (qs + q_bias_r) * 0.125f);
                }
            }
        }
        gsync(flags, golines, ++bc, blk);

        // ===== Phase D: attention (blocks 0..127, t>0) =====
        if (blk < 128 && t > 0) {
            const int b = blk >> 4, anh = blk & 15;
            if (tid < 32) *(float2*)(lds + S_Q + tid * 2) = ld2(qb + b * 1024 + anh * 64 + tid * 2);
            __syncthreads();
            float sc = -1e30f;
            if (tid < t) {
                const float* kr = Kb + ((size_t)tid * 8 + b) * 1024 + anh * 64;
                float d = 0.f;
                #pragma unroll
                for (int j = 0; j < 16; ++j) {
                    const float4 k4 = ld4(kr + j * 4);
                    d += k4.x*lds[S_Q + j*4]   + k4.y*lds[S_Q + j*4+1]
                       + k4.z*lds[S_Q + j*4+2] + k4.w*lds[S_Q + j*4+3];
                }
                sc = d;
            }
            float mx = sc;
            #pragma unroll
            for (int o = 1; o < 64; o <<= 1) mx = fmaxf(mx, __shfl_xor(mx, o));
            if (l == 0) lds[S_RED + w] = mx;
            __syncthreads();
            mx = lds[S_RED];
            #pragma unroll
            for (int j = 1; j < 8; ++j) mx = fmaxf(mx, lds[S_RED + j]);
            const float p = (tid < t) ? __expf(sc - mx) : 0.f;
            if (tid < 256) lds[S_PS + tid] = p;
            float ps = p;
            #pragma unroll
            for (int o = 1; o < 64; o <<= 1) ps += __shfl_xor(ps, o);
            if (l == 0) lds[S_R2 + w] = ps;
            __syncthreads();
            float tot = lds[S_R2];
            #pragma unroll
            for (int j = 1; j < 8; ++j) tot += lds[S_R2 + j];
            const float inv = 1.f / tot;
            // PV: thread = (dh2 float2-col, ss s-offset of 16)
            const int dh2 = tid & 31, ss = tid >> 5;
            float cax = 0.f, cay = 0.f;
            for (int s2 = ss; s2 < t; s2 += 16) {
                const float pp = lds[S_PS + s2];
                const float2 v2 = ld2(Vb + ((size_t)s2 * 8 + b) * 1024 + anh * 64 + dh2 * 2);
                cax += pp * v2.x; cay += pp * v2.y;
            }
            *(float2*)(lds + S_STAGE + tid * 2) = make_float2(cax, cay);
            __syncthreads();
            if (tid < 64) {
                float v = 0.f;
                #pragma unroll
                for (int j = 0; j < 16; ++j) v += lds[S_STAGE + j * 64 + tid];
                st1(ctx + b * 1024 + anh * 64 + tid, v * inv);
            }
        }
        gsync(flags, golines, ++bc, blk);

        // ===== Phase E: out-proj (cached Wo, 4 rows) + hx update + emit =====
        {
            if (tid < 32)
                lds[S_EH + tid] = ld1(h0g + (size_t)(tid >> 2) * 1024 + blk * 4 + (tid & 3));
            const int b = w;
            float o0 = 0.f, o1 = 0.f, o2 = 0.f, o3 = 0.f;
            if (t > 0) {
                const float* cb = ctx + b * 1024;
                #pragma unroll
                for (int i = 0; i < 4; ++i) {
                    const int k = i * 256 + l * 4;
                    const float4 c4 = ld4(cb + k);
                    o0 += dot4(*(const float4*)(Wo + (size_t)(blk*4+0) * 1024 + k), c4);
                    o1 += dot4(*(const float4*)(Wo + (size_t)(blk*4+1) * 1024 + k), c4);
                    o2 += dot4(*(const float4*)(Wo + (size_t)(blk*4+2) * 1024 + k), c4);
                    o3 += dot4(*(const float4*)(Wo + (size_t)(blk*4+3) * 1024 + k), c4);
                }
                #pragma unroll
                for (int o = 1; o < 64; o <<= 1) {
                    o0 += __shfl_xor(o0, o); o1 += __shfl_xor(o1, o);
                    o2 += __shfl_xor(o2, o); o3 += __shfl_xor(o3, o);
                }
            }
            __syncthreads();
            if (l == 0) {
                const float v0 = (t > 0) ? lds[S_EH + w*4 + 0] + o0 + bo0 : lds[S_EH + w*4 + 0];
                const float v1 = (t > 0) ? lds[S_EH + w*4 + 1] + o1 + bo1 : lds[S_EH + w*4 + 1];
                const float v2 = (t > 0) ? lds[S_EH + w*4 + 2] + o2 + bo2 : lds[S_EH + w*4 + 2];
                const float v3 = (t > 0) ? lds[S_EH + w*4 + 3] + o3 + bo3 : lds[S_EH + w*4 + 3];
                st1(hx + b * 1024 + blk*4 + 0, v0);
                st1(hx + b * 1024 + blk*4 + 1, v1);
                st1(hx + b * 1024 + blk*4 + 2, v2);
                st1(hx + b * 1024 + blk*4 + 3, v3);
                float* op = out + (size_t)t * 8192 + b * 1024 + blk * 4;
                op[0] = v0; op[1] = v1; op[2] = v2; op[3] = v3;
            }
        }
        // post-E barrier is the top-of-loop gsync of step t+1
    }
    gsync(flags, golines, ++bc, blk);

    // epilogue: final cx (from replicas) and hx
    if ((blk & 31) == 0) {
        const int b = blk >> 5;
        out[2097152 + 8192 + b * 1024 + tid]       = lds[S_CX + tid];
        out[2097152 + 8192 + b * 1024 + 512 + tid] = lds[S_CX + 512 + tid];
    }
    if (blk >= 136 && blk < 144) {
        const int b = blk - 136;
        out[2097152 + b * 1024 + tid]       = ld1(hx + b * 1024 + tid);
        out[2097152 + b * 1024 + 512 + tid] = ld1(hx + b * 1024 + 512 + tid);
    }
}

extern "C" void kernel_launch(void* const* d_in, const int* in_sizes, int n_in,
                              void* d_out, int out_size, void* d_ws, size_t ws_size,
                              hipStream_t stream) {
    const float* x   = (const float*)d_in[0];
    const float* Wg  = (const float*)d_in[1];
    const float* bg  = (const float*)d_in[2];
    const float* lng = (const float*)d_in[3];
    const float* lnb = (const float*)d_in[4];
    const float* Wq  = (const float*)d_in[5];
    const float* Wk  = (const float*)d_in[6];
    const float* Wv  = (const float*)d_in[7];
    const float* bq  = (const float*)d_in[8];
    const float* bk  = (const float*)d_in[9];
    const float* bv  = (const float*)d_in[10];
    const float* Wo  = (const float*)d_in[11];
    const float* bo  = (const float*)d_in[12];
    float* out = (float*)d_out;
    float* ws  = (float*)d_ws;

    static int attr_set = 0;
    if (!attr_set) {
        hipFuncSetAttribute((const void*)qlstm_kernel,
                            hipFuncAttributeMaxDynamicSharedMemorySize, LDS_BYTES);
        attr_set = 1;
    }
    // zero barrier flags + go lines (graph-captured; deterministic per replay)
    hipMemsetAsync((char*)d_ws + (size_t)OFF_FLAGS * 4, 0, (4096 + 128) * 4, stream);

    void* args[] = { &x, &Wg, &bg, &lng, &lnb, &Wq, &Wk, &Wv,
                     &bq, &bk, &bv, &Wo, &bo, &out, &ws };
    hipLaunchCooperativeKernel((void*)qlstm_kernel, dim3(NBLK), dim3(NTHR),
                               args, LDS_BYTES, stream);
}